// Round 2
// baseline (939.486 us; speedup 1.0000x reference)
//
#include <hip/hip_runtime.h>
#include <hip/hip_bf16.h>
#include <stdint.h>

#define IN_DIM 256
#define HID 16
#define OUTD 10
#define BKT_SHIFT 8            // 256 nodes per bucket
#define BKT_W 256
#define PART_CH 4096           // edges per partition block
#define EPT 16                 // edges per thread in part (PART_CH/256)

typedef short v8s __attribute__((ext_vector_type(8)));
typedef float v4f __attribute__((ext_vector_type(4)));

__device__ __forceinline__ float bf2f(unsigned short u) {
    return __uint_as_float(((unsigned int)u) << 16);
}
__device__ __forceinline__ unsigned short f2bf(float f) {
    unsigned int u = __float_as_uint(f);
    unsigned int lsb = (u >> 16) & 1u;
    u += 0x7fffu + lsb;  // round-to-nearest-even
    return (unsigned short)(u >> 16);
}

__device__ __forceinline__ int load_dst(const void* ei, int n_edges, int e, int is64) {
    return is64 ? (int)((const long long*)ei)[(size_t)n_edges + e]
                : ((const int*)ei)[(size_t)n_edges + e];
}
__device__ __forceinline__ int load_src(const void* ei, int n_edges, int e, int is64) {
    return is64 ? (int)((const long long*)ei)[e] : ((const int*)ei)[e];
}

// ---------------- setup: parallel dtype detect + zero bucket counters -------
__global__ void setup_kernel(const void* __restrict__ x,
                             const void* __restrict__ W1,
                             const void* __restrict__ ei,
                             int n_nodes, int* __restrict__ flags,
                             int* __restrict__ bucket_cnt, int K) {
    int t = threadIdx.x;
    for (int i = t; i < K; i += blockDim.x) bucket_cnt[i] = 0;
    if (t < 64) {
        const unsigned short* xs = (const unsigned short*)x;
        const unsigned short* ws = (const unsigned short*)W1;
        bool badx = false, badw = false;
#pragma unroll
        for (int q = 0; q < 4; ++q) {
            float vx = bf2f(xs[t + 64 * q]);
            float vw = bf2f(ws[t + 64 * q]);
            if (!(vx > -1e4f && vx < 1e4f)) badx = true;
            if (!(vw > -1e4f && vw < 1e4f)) badw = true;
        }
        const unsigned long long* e64 = (const unsigned long long*)ei;
        bool big = false;
#pragma unroll
        for (int q = 0; q < 2; ++q)
            if (e64[t + 64 * q] >= (unsigned long long)n_nodes) big = true;
        int xf32 = __any(badx) ? 1 : 0;
        int wf32 = __any(badw) ? 1 : 0;
        int is64 = __any(big) ? 0 : 1;
        if (t == 0) { flags[0] = is64; flags[1] = xf32; flags[2] = wf32; }
    }
}

// ---------------- bucket histogram ------------------------------------------
__global__ void bhist_kernel(const void* __restrict__ ei, int n_edges,
                             int* __restrict__ bucket_cnt,
                             const int* __restrict__ flags, int K) {
    extern __shared__ int lh[];
    for (int i = threadIdx.x; i < K; i += blockDim.x) lh[i] = 0;
    __syncthreads();
    int is64 = flags[0];
    int t = blockIdx.x * blockDim.x + threadIdx.x;
    int stride = gridDim.x * blockDim.x;
    for (int e = t; e < n_edges; e += stride) {
        int d = load_dst(ei, n_edges, e, is64);
        atomicAdd(&lh[d >> BKT_SHIFT], 1);
    }
    __syncthreads();
    for (int i = threadIdx.x; i < K; i += blockDim.x)
        if (lh[i]) atomicAdd(&bucket_cnt[i], lh[i]);
}

// ---------------- bucket scan (1 block) -------------------------------------
__global__ void bscan_kernel(const int* __restrict__ bucket_cnt, int K,
                             int* __restrict__ bucket_off, int* __restrict__ bcur) {
    __shared__ int ts[256];
    int t = threadIdx.x;
    const int KP = (K + 255) / 256;   // <= 8
    int base = t * KP;
    int local[8];
    int s = 0;
    for (int q = 0; q < KP; ++q) {
        int idx = base + q;
        int v = (idx < K) ? bucket_cnt[idx] : 0;
        local[q] = v; s += v;
    }
    ts[t] = s;
    __syncthreads();
    for (int off = 1; off < 256; off <<= 1) {
        int v = (t >= off) ? ts[t - off] : 0;
        __syncthreads();
        ts[t] += v;
        __syncthreads();
    }
    int ex = ts[t] - s;
    for (int q = 0; q < KP; ++q) {
        int idx = base + q;
        if (idx < K) { bucket_off[idx] = ex; bcur[idx] = ex; }
        ex += local[q];
    }
    if (t == 255) bucket_off[K] = ex;
}

// ---------------- partition: in-LDS counting sort + coalesced flush ---------
// pair = (src << 8) | (dst & 255): 4B packed; output sorted by bucket.
__global__ void part_kernel(const void* __restrict__ ei, int n_edges,
                            int* __restrict__ bcur, unsigned int* __restrict__ pairs,
                            const int* __restrict__ flags, int K) {
    __shared__ int lh[512];                  // counts, then placement cursor
    __shared__ int gdelta[512];              // gstart[b] - lstart[b]
    __shared__ int ts[256];
    __shared__ unsigned int spairs[PART_CH]; // 16 KiB
    __shared__ unsigned short sbkt[PART_CH]; // 8 KiB
    int begin = blockIdx.x * PART_CH;
    int is64 = flags[0];
    int t = threadIdx.x;
    lh[t] = 0; lh[t + 256] = 0;

    int dloc[EPT];
#pragma unroll
    for (int i = 0; i < EPT; ++i) {
        int e = begin + i * 256 + t;
        dloc[i] = (e < n_edges) ? load_dst(ei, n_edges, e, is64) : -1;
    }
    __syncthreads();
#pragma unroll
    for (int i = 0; i < EPT; ++i)
        if (dloc[i] >= 0) atomicAdd(&lh[dloc[i] >> BKT_SHIFT], 1);
    __syncthreads();

    // block scan over 512 bucket counts (thread t owns entries 2t, 2t+1)
    int c0 = lh[2 * t], c1 = lh[2 * t + 1];
    int s = c0 + c1;
    ts[t] = s;
    __syncthreads();
    for (int off = 1; off < 256; off <<= 1) {
        int v = (t >= off) ? ts[t - off] : 0;
        __syncthreads();
        ts[t] += v;
        __syncthreads();
    }
    int ex = ts[t] - s;
    // reserve global runs; cursor = local exclusive start
    if (c0 > 0) gdelta[2 * t]     = atomicAdd(&bcur[2 * t], c0) - ex;
    if (c1 > 0) gdelta[2 * t + 1] = atomicAdd(&bcur[2 * t + 1], c1) - (ex + c0);
    __syncthreads();   // everyone done reading lh counts before overwrite
    lh[2 * t] = ex; lh[2 * t + 1] = ex + c0;
    __syncthreads();

    // place into LDS, sorted by bucket
#pragma unroll
    for (int i = 0; i < EPT; ++i) {
        int e = begin + i * 256 + t;
        if (dloc[i] >= 0) {
            int srcv = load_src(ei, n_edges, e, is64);
            int b = dloc[i] >> BKT_SHIFT;
            int lpos = atomicAdd(&lh[b], 1);
            spairs[lpos] = ((unsigned)srcv << 8) | ((unsigned)dloc[i] & (BKT_W - 1));
            sbkt[lpos] = (unsigned short)b;
        }
    }
    __syncthreads();

    // coalesced flush: ascending j walks bucket runs contiguously
    int total = n_edges - begin; if (total > PART_CH) total = PART_CH;
    for (int j = t; j < total; j += 256)
        pairs[gdelta[sbkt[j]] + j] = spairs[j];
}

// ---------------- gemm1 unified: m1 = x @ W1 (bf16 or fp32 x) ---------------
__global__ __launch_bounds__(256) void gemm1_kernel(
        const void* __restrict__ xp_, const void* __restrict__ W1p,
        float* __restrict__ m1, int n_nodes, const int* __restrict__ flags) {
    __shared__ unsigned short Bbuf[8192];   // 16 KiB, unions both paths
    int t = threadIdx.x;
    const int xf32 = flags[1], wf32 = flags[2];
    int lane = t & 63;
    int wave = t >> 6;
    int col  = lane & 15;
    int quad = lane >> 4;
    int n_tiles = (n_nodes + 15) >> 4;

    if (!xf32) {
        // ---------- bf16 x path ----------
        unsigned short* Bl = Bbuf;
        for (int i = t; i < 4096; i += 256) {      // i = k*16 + n
            unsigned short w = wf32 ? f2bf(((const float*)W1p)[i])
                                    : ((const unsigned short*)W1p)[i];
            int k = i >> 4, n = i & 15;
            int kk = k >> 5, qd = (k >> 3) & 3, j = k & 7;
            Bl[((kk * 4 + qd) * 16 + n) * 8 + j] = w;
        }
        __syncthreads();
        v8s bfrag[8];
#pragma unroll
        for (int kk = 0; kk < 8; ++kk)
            bfrag[kk] = *(const v8s*)&Bl[(kk * 64 + lane) * 8];
        const unsigned short* x = (const unsigned short*)xp_;
        for (int tile = blockIdx.x * 4 + wave; tile < n_tiles; tile += gridDim.x * 4) {
            int row = tile * 16 + col;
            int r = row < n_nodes ? row : n_nodes - 1;
            const unsigned short* xp = x + (size_t)r * IN_DIM + quad * 8;
            v8s a[8];
#pragma unroll
            for (int kk = 0; kk < 8; ++kk)
                a[kk] = *(const v8s*)(xp + kk * 32);
            v4f acc = {0.f, 0.f, 0.f, 0.f};
#pragma unroll
            for (int kk = 0; kk < 8; ++kk)
                acc = __builtin_amdgcn_mfma_f32_16x16x32_bf16(a[kk], bfrag[kk], acc, 0, 0, 0);
#pragma unroll
            for (int rg = 0; rg < 4; ++rg) {
                int node = tile * 16 + quad * 4 + rg;
                if (node < n_nodes) m1[(size_t)node * HID + col] = acc[rg];
            }
        }
    } else {
        // ---------- fp32 x path: split-bf16, fp32-grade ----------
        unsigned short* Bhi = Bbuf;
        unsigned short* Blo = Bbuf + 4096;
        for (int i = t; i < 4096; i += 256) {
            float w = wf32 ? ((const float*)W1p)[i]
                           : bf2f(((const unsigned short*)W1p)[i]);
            unsigned short hi = f2bf(w);
            unsigned short lo = f2bf(w - bf2f(hi));
            int k = i >> 4, n = i & 15;
            int kk = k >> 5, qd = (k >> 3) & 3, j = k & 7;
            int idx = ((kk * 4 + qd) * 16 + n) * 8 + j;
            Bhi[idx] = hi; Blo[idx] = lo;
        }
        __syncthreads();
        const float* x = (const float*)xp_;
        for (int tile = blockIdx.x * 4 + wave; tile < n_tiles; tile += gridDim.x * 4) {
            int row = tile * 16 + col;
            int r = row < n_nodes ? row : n_nodes - 1;
            const float* xp = x + (size_t)r * IN_DIM + quad * 8;
            // prefetch: 16 independent dwordx4 loads (64 floats/lane)
            float4 u[16];
#pragma unroll
            for (int kk = 0; kk < 8; ++kk) {
                u[2 * kk]     = *(const float4*)(xp + kk * 32);
                u[2 * kk + 1] = *(const float4*)(xp + kk * 32 + 4);
            }
            v4f acc = {0.f, 0.f, 0.f, 0.f};
#pragma unroll
            for (int kk = 0; kk < 8; ++kk) {
                float uv[8] = {u[2 * kk].x,     u[2 * kk].y,
                               u[2 * kk].z,     u[2 * kk].w,
                               u[2 * kk + 1].x, u[2 * kk + 1].y,
                               u[2 * kk + 1].z, u[2 * kk + 1].w};
                v8s ahi, alo;
#pragma unroll
                for (int j = 0; j < 8; ++j) {
                    unsigned short hi = f2bf(uv[j]);
                    unsigned short lo = f2bf(uv[j] - bf2f(hi));
                    ahi[j] = (short)hi; alo[j] = (short)lo;
                }
                v8s bh = *(const v8s*)&Bhi[(kk * 64 + lane) * 8];
                v8s bl = *(const v8s*)&Blo[(kk * 64 + lane) * 8];
                acc = __builtin_amdgcn_mfma_f32_16x16x32_bf16(ahi, bh, acc, 0, 0, 0);
                acc = __builtin_amdgcn_mfma_f32_16x16x32_bf16(ahi, bl, acc, 0, 0, 0);
                acc = __builtin_amdgcn_mfma_f32_16x16x32_bf16(alo, bh, acc, 0, 0, 0);
            }
#pragma unroll
            for (int rg = 0; rg < 4; ++rg) {
                int node = tile * 16 + quad * 4 + rg;
                if (node < n_nodes) m1[(size_t)node * HID + col] = acc[rg];
            }
        }
    }
}

// ---------------- agg1: edge-parallel bucket accumulation -------------------
// One block per 256-dst bucket; pairs already bucket-sorted. 4 lanes/edge
// gather the 64B m1[src] line; ds_add_f32 into LDS acc[256][16]. Writes RAW
// aggregate (bias+relu applied by the consumer, agg2). No CSR needed.
__global__ __launch_bounds__(1024, 4) void agg1_bucket(
        const float* __restrict__ m1,
        const unsigned int* __restrict__ pairs,
        const int* __restrict__ bucket_off,
        float* __restrict__ h, int n_nodes) {
    __shared__ float acc[BKT_W * HID];      // 16 KiB
    int t = threadIdx.x;
    for (int i = t; i < BKT_W * HID; i += 1024) acc[i] = 0.f;
    __syncthreads();

    int blk = blockIdx.x;
    int nbase = blk << BKT_SHIFT;
    int beg = bucket_off[blk], end = bucket_off[blk + 1];
    int q = t & 3;
    for (int k = beg + (t >> 2); k < end; k += 256) {
        unsigned int p = pairs[k];
        int src = (int)(p >> 8);
        int dl  = (int)(p & (BKT_W - 1));
        float4 v = *((const float4*)(m1 + (size_t)src * HID) + q);
        float* a = &acc[(dl << 4) + (q << 2)];
        atomicAdd(&a[0], v.x);
        atomicAdd(&a[1], v.y);
        atomicAdd(&a[2], v.z);
        atomicAdd(&a[3], v.w);
    }
    __syncthreads();

    int NL = n_nodes - nbase; if (NL > BKT_W) NL = BKT_W;
    float4* hd = (float4*)(h + (size_t)nbase * HID);
    const float4* as = (const float4*)acc;
    for (int i = t; i < NL * 4; i += 1024) hd[i] = as[i];
}

// ---------------- agg2 + out fused: out = (A . relu(h+b1)) @ W2 + b2 --------
__global__ __launch_bounds__(1024, 4) void agg2_out_bucket(
        const float* __restrict__ h,
        const unsigned int* __restrict__ pairs,
        const int* __restrict__ bucket_off,
        const void* __restrict__ b1p,
        const void* __restrict__ W2p,
        const void* __restrict__ b2p,
        void* __restrict__ out, int n_nodes,
        const int* __restrict__ flags) {
    __shared__ float acc[BKT_W * HID];      // 16 KiB
    __shared__ float Ws[HID * OUTD];
    __shared__ float b1s[HID];
    __shared__ float bs[OUTD];
    const int xf32 = flags[1], wf32 = flags[2];
    int t = threadIdx.x;
    if (t < HID * OUTD)
        Ws[t] = wf32 ? ((const float*)W2p)[t] : bf2f(((const unsigned short*)W2p)[t]);
    if (t < HID)
        b1s[t] = wf32 ? ((const float*)b1p)[t] : bf2f(((const unsigned short*)b1p)[t]);
    if (t < OUTD)
        bs[t] = wf32 ? ((const float*)b2p)[t] : bf2f(((const unsigned short*)b2p)[t]);
    for (int i = t; i < BKT_W * HID; i += 1024) acc[i] = 0.f;
    __syncthreads();

    int blk = blockIdx.x;
    int nbase = blk << BKT_SHIFT;
    int beg = bucket_off[blk], end = bucket_off[blk + 1];
    int q = t & 3;
    float bq0 = b1s[q * 4 + 0], bq1 = b1s[q * 4 + 1];
    float bq2 = b1s[q * 4 + 2], bq3 = b1s[q * 4 + 3];
    for (int k = beg + (t >> 2); k < end; k += 256) {
        unsigned int p = pairs[k];
        int src = (int)(p >> 8);
        int dl  = (int)(p & (BKT_W - 1));
        float4 v = *((const float4*)(h + (size_t)src * HID) + q);
        v.x = fmaxf(v.x + bq0, 0.f);
        v.y = fmaxf(v.y + bq1, 0.f);
        v.z = fmaxf(v.z + bq2, 0.f);
        v.w = fmaxf(v.w + bq3, 0.f);
        float* a = &acc[(dl << 4) + (q << 2)];
        atomicAdd(&a[0], v.x);
        atomicAdd(&a[1], v.y);
        atomicAdd(&a[2], v.z);
        atomicAdd(&a[3], v.w);
    }
    __syncthreads();

    int NL = n_nodes - nbase; if (NL > BKT_W) NL = BKT_W;
    for (int c = t; c < NL * OUTD; c += 1024) {
        int node = c / OUTD;
        int od = c - node * OUTD;
        const float* an = &acc[node << 4];
        float s = bs[od];
#pragma unroll
        for (int j = 0; j < HID; ++j) s = fmaf(an[j], Ws[j * OUTD + od], s);
        size_t oi = (size_t)(nbase + node) * OUTD + od;
        if (xf32) ((float*)out)[oi] = s;
        else      ((unsigned short*)out)[oi] = f2bf(s);
    }
}

// ---------------- Sentinel: ws_size too small -------------------------------
__global__ void sentinel_kernel(float* __restrict__ out) {
    if (blockIdx.x == 0 && threadIdx.x < 16) out[threadIdx.x] = 123456.0f;
}

extern "C" void kernel_launch(void* const* d_in, const int* in_sizes, int n_in,
                              void* d_out, int out_size, void* d_ws, size_t ws_size,
                              hipStream_t stream) {
    const void* x  = d_in[0];
    const void* ei = d_in[1];
    const void* W1 = d_in[2];
    const void* b1 = d_in[3];
    const void* W2 = d_in[4];
    const void* b2 = d_in[5];

    const int n_nodes = in_sizes[0] / IN_DIM;        // 100000
    const int n_edges = in_sizes[1] / 2;             // 3200000
    const int K = (n_nodes + BKT_W - 1) / BKT_W;     // 391 buckets

    // Workspace layout (256B-aligned):
    // [flags | bucket_cnt | bucket_off | bcur | pairs | m1 | h]
    // pairs stays live through both agg kernels now (no aliasing with m1/h).
    char* p = (char*)d_ws;
    auto align = [](size_t v) { return (v + 255) & ~(size_t)255; };
    size_t off = 0;
    int* flags      = (int*)(p + off); off = align(off + 256);
    int* bucket_cnt = (int*)(p + off); off = align(off + (size_t)K * 4);
    int* bucket_off = (int*)(p + off); off = align(off + ((size_t)K + 1) * 4);
    int* bcur       = (int*)(p + off); off = align(off + (size_t)K * 4);
    unsigned int* pairs = (unsigned int*)(p + off); off = align(off + (size_t)n_edges * 4);
    float* m1 = (float*)(p + off); off = align(off + (size_t)n_nodes * HID * 4);
    float* h  = (float*)(p + off); off = align(off + (size_t)n_nodes * HID * 4);

    if (ws_size < off) {
        sentinel_kernel<<<1, 64, 0, stream>>>((float*)d_out);
        return;
    }

    const size_t lds_k = (size_t)K * 4;

    // --- bucket-sorted edge list build (no per-node CSR) ---
    setup_kernel<<<1, 256, 0, stream>>>(x, W1, ei, n_nodes, flags, bucket_cnt, K);
    bhist_kernel<<<1024, 256, lds_k, stream>>>(ei, n_edges, bucket_cnt, flags, K);
    bscan_kernel<<<1, 256, 0, stream>>>(bucket_cnt, K, bucket_off, bcur);
    part_kernel<<<(n_edges + PART_CH - 1) / PART_CH, 256, 0, stream>>>(
        ei, n_edges, bcur, pairs, flags, K);

    // --- layer 1 GEMM (unified dtype paths) ---
    {
        int n_tiles16 = (n_nodes + 15) >> 4;          // 6250
        int g1 = (n_tiles16 + 3) / 4;                 // 1 tile per wave
        gemm1_kernel<<<g1, 256, 0, stream>>>(x, W1, m1, n_nodes, flags);
    }

    // --- layer 1 aggregation (edge-parallel, bucketed) ---
    agg1_bucket<<<K, 1024, 0, stream>>>(m1, pairs, bucket_off, h, n_nodes);

    // --- layer 2 aggregation + output GEMM fused ---
    agg2_out_bucket<<<K, 1024, 0, stream>>>(h, pairs, bucket_off, b1, W2, b2,
                                            d_out, n_nodes, flags);
}

// Round 3
// 338.889 us; speedup vs baseline: 2.7723x; 2.7723x over previous
//
#include <hip/hip_runtime.h>
#include <hip/hip_bf16.h>
#include <stdint.h>

#define IN_DIM 256
#define HID 16
#define OUTD 10
#define BKT_SHIFT 8            // 256 nodes per bucket
#define BKT_W 256
#define PART_CH 4096           // edges per partition block
#define EPT 16                 // edges per thread in part (PART_CH/256)

typedef short v8s __attribute__((ext_vector_type(8)));
typedef float v4f __attribute__((ext_vector_type(4)));

__device__ __forceinline__ float bf2f(unsigned short u) {
    return __uint_as_float(((unsigned int)u) << 16);
}
__device__ __forceinline__ unsigned short f2bf(float f) {
    unsigned int u = __float_as_uint(f);
    unsigned int lsb = (u >> 16) & 1u;
    u += 0x7fffu + lsb;  // round-to-nearest-even
    return (unsigned short)(u >> 16);
}

__device__ __forceinline__ int load_dst(const void* ei, int n_edges, int e, int is64) {
    return is64 ? (int)((const long long*)ei)[(size_t)n_edges + e]
                : ((const int*)ei)[(size_t)n_edges + e];
}
__device__ __forceinline__ int load_src(const void* ei, int n_edges, int e, int is64) {
    return is64 ? (int)((const long long*)ei)[e] : ((const int*)ei)[e];
}

// ---------------- setup: parallel dtype detect + zero bucket counters -------
__global__ void setup_kernel(const void* __restrict__ x,
                             const void* __restrict__ W1,
                             const void* __restrict__ ei,
                             int n_nodes, int* __restrict__ flags,
                             int* __restrict__ bucket_cnt, int K) {
    int t = threadIdx.x;
    for (int i = t; i < K; i += blockDim.x) bucket_cnt[i] = 0;
    if (t < 64) {
        const unsigned short* xs = (const unsigned short*)x;
        const unsigned short* ws = (const unsigned short*)W1;
        bool badx = false, badw = false;
#pragma unroll
        for (int q = 0; q < 4; ++q) {
            float vx = bf2f(xs[t + 64 * q]);
            float vw = bf2f(ws[t + 64 * q]);
            if (!(vx > -1e4f && vx < 1e4f)) badx = true;
            if (!(vw > -1e4f && vw < 1e4f)) badw = true;
        }
        const unsigned long long* e64 = (const unsigned long long*)ei;
        bool big = false;
#pragma unroll
        for (int q = 0; q < 2; ++q)
            if (e64[t + 64 * q] >= (unsigned long long)n_nodes) big = true;
        int xf32 = __any(badx) ? 1 : 0;
        int wf32 = __any(badw) ? 1 : 0;
        int is64 = __any(big) ? 0 : 1;
        if (t == 0) { flags[0] = is64; flags[1] = xf32; flags[2] = wf32; }
    }
}

// ---------------- bucket histogram ------------------------------------------
__global__ void bhist_kernel(const void* __restrict__ ei, int n_edges,
                             int* __restrict__ bucket_cnt,
                             const int* __restrict__ flags, int K) {
    extern __shared__ int lh[];
    for (int i = threadIdx.x; i < K; i += blockDim.x) lh[i] = 0;
    __syncthreads();
    int is64 = flags[0];
    int t = blockIdx.x * blockDim.x + threadIdx.x;
    int stride = gridDim.x * blockDim.x;
    for (int e = t; e < n_edges; e += stride) {
        int d = load_dst(ei, n_edges, e, is64);
        atomicAdd(&lh[d >> BKT_SHIFT], 1);
    }
    __syncthreads();
    for (int i = threadIdx.x; i < K; i += blockDim.x)
        if (lh[i]) atomicAdd(&bucket_cnt[i], lh[i]);
}

// ---------------- bucket scan (1 block) -------------------------------------
__global__ void bscan_kernel(const int* __restrict__ bucket_cnt, int K,
                             int* __restrict__ bucket_off, int* __restrict__ bcur,
                             int* __restrict__ row_off, int n_nodes, int n_edges) {
    __shared__ int ts[256];
    int t = threadIdx.x;
    const int KP = (K + 255) / 256;   // <= 8
    int base = t * KP;
    int local[8];
    int s = 0;
    for (int q = 0; q < KP; ++q) {
        int idx = base + q;
        int v = (idx < K) ? bucket_cnt[idx] : 0;
        local[q] = v; s += v;
    }
    ts[t] = s;
    __syncthreads();
    for (int off = 1; off < 256; off <<= 1) {
        int v = (t >= off) ? ts[t - off] : 0;
        __syncthreads();
        ts[t] += v;
        __syncthreads();
    }
    int ex = ts[t] - s;
    for (int q = 0; q < KP; ++q) {
        int idx = base + q;
        if (idx < K) { bucket_off[idx] = ex; bcur[idx] = ex; }
        ex += local[q];
    }
    if (t == 255) bucket_off[K] = ex;
    if (t == 0) row_off[n_nodes] = n_edges;
}

// ---------------- partition: in-LDS counting sort + coalesced flush ---------
// pair = (src << 8) | (dst & 255): 4B packed; output sorted by bucket.
__global__ void part_kernel(const void* __restrict__ ei, int n_edges,
                            int* __restrict__ bcur, unsigned int* __restrict__ pairs,
                            const int* __restrict__ flags, int K) {
    __shared__ int lh[512];                  // counts, then placement cursor
    __shared__ int gdelta[512];              // gstart[b] - lstart[b]
    __shared__ int ts[256];
    __shared__ unsigned int spairs[PART_CH]; // 16 KiB
    __shared__ unsigned short sbkt[PART_CH]; // 8 KiB
    int begin = blockIdx.x * PART_CH;
    int is64 = flags[0];
    int t = threadIdx.x;
    lh[t] = 0; lh[t + 256] = 0;

    int dloc[EPT];
#pragma unroll
    for (int i = 0; i < EPT; ++i) {
        int e = begin + i * 256 + t;
        dloc[i] = (e < n_edges) ? load_dst(ei, n_edges, e, is64) : -1;
    }
    __syncthreads();
#pragma unroll
    for (int i = 0; i < EPT; ++i)
        if (dloc[i] >= 0) atomicAdd(&lh[dloc[i] >> BKT_SHIFT], 1);
    __syncthreads();

    // block scan over 512 bucket counts (thread t owns entries 2t, 2t+1)
    int c0 = lh[2 * t], c1 = lh[2 * t + 1];
    int s = c0 + c1;
    ts[t] = s;
    __syncthreads();
    for (int off = 1; off < 256; off <<= 1) {
        int v = (t >= off) ? ts[t - off] : 0;
        __syncthreads();
        ts[t] += v;
        __syncthreads();
    }
    int ex = ts[t] - s;
    // reserve global runs; cursor = local exclusive start
    if (c0 > 0) gdelta[2 * t]     = atomicAdd(&bcur[2 * t], c0) - ex;
    if (c1 > 0) gdelta[2 * t + 1] = atomicAdd(&bcur[2 * t + 1], c1) - (ex + c0);
    __syncthreads();   // everyone done reading lh counts before overwrite
    lh[2 * t] = ex; lh[2 * t + 1] = ex + c0;
    __syncthreads();

    // place into LDS, sorted by bucket
#pragma unroll
    for (int i = 0; i < EPT; ++i) {
        int e = begin + i * 256 + t;
        if (dloc[i] >= 0) {
            int srcv = load_src(ei, n_edges, e, is64);
            int b = dloc[i] >> BKT_SHIFT;
            int lpos = atomicAdd(&lh[b], 1);
            spairs[lpos] = ((unsigned)srcv << 8) | ((unsigned)dloc[i] & (BKT_W - 1));
            sbkt[lpos] = (unsigned short)b;
        }
    }
    __syncthreads();

    // coalesced flush: ascending j walks bucket runs contiguously
    int total = n_edges - begin; if (total > PART_CH) total = PART_CH;
    for (int j = t; j < total; j += 256)
        pairs[gdelta[sbkt[j]] + j] = spairs[j];
}

// ---------------- per-bucket CSR build (256-node buckets, 512 thr) ----------
__global__ void csr_kernel(const unsigned int* __restrict__ pairs,
                           const int* __restrict__ bucket_off,
                           int* __restrict__ row_off, int* __restrict__ csr_src,
                           int n_nodes) {
    __shared__ int deg[BKT_W];
    __shared__ int cur[BKT_W];
    __shared__ int ts[BKT_W];
    int blk = blockIdx.x;
    int nbase = blk << BKT_SHIFT;
    int NL = n_nodes - nbase; if (NL > BKT_W) NL = BKT_W;
    int beg = bucket_off[blk], end = bucket_off[blk + 1];
    int t = threadIdx.x;
    if (t < BKT_W) deg[t] = 0;
    __syncthreads();
    for (int k = beg + t; k < end; k += blockDim.x)
        atomicAdd(&deg[pairs[k] & (BKT_W - 1)], 1);
    __syncthreads();
    if (t < BKT_W) ts[t] = deg[t];
    __syncthreads();
    for (int off = 1; off < BKT_W; off <<= 1) {
        int v = 0;
        if (t < BKT_W && t >= off) v = ts[t - off];
        __syncthreads();
        if (t < BKT_W) ts[t] += v;
        __syncthreads();
    }
    if (t < BKT_W) {
        int ex = beg + ts[t] - deg[t];
        cur[t] = ex;
        if (t < NL) row_off[nbase + t] = ex;
    }
    __syncthreads();
    for (int k = beg + t; k < end; k += blockDim.x) {
        unsigned int p = pairs[k];
        int pos = atomicAdd(&cur[p & (BKT_W - 1)], 1);
        csr_src[pos] = (int)(p >> 8);
    }
}

// ---------------- gemm1 unified: m1 = bf16(x @ W1) --------------------------
// 2 tiles per wave, all 32 x-loads issued before convert/MFMA (latency hide).
// m1 stored bf16: 3.2 MB -> fits a single XCD L2 for the agg gathers.
__global__ __launch_bounds__(256) void gemm1_kernel(
        const void* __restrict__ xp_, const void* __restrict__ W1p,
        unsigned short* __restrict__ m1, int n_nodes,
        const int* __restrict__ flags) {
    __shared__ unsigned short Bbuf[8192];   // 16 KiB, unions both paths
    int t = threadIdx.x;
    const int xf32 = flags[1], wf32 = flags[2];
    int lane = t & 63;
    int wave = t >> 6;
    int col  = lane & 15;
    int quad = lane >> 4;
    int n_tiles = (n_nodes + 15) >> 4;

    if (!xf32) {
        // ---------- bf16 x path ----------
        unsigned short* Bl = Bbuf;
        for (int i = t; i < 4096; i += 256) {      // i = k*16 + n
            unsigned short w = wf32 ? f2bf(((const float*)W1p)[i])
                                    : ((const unsigned short*)W1p)[i];
            int k = i >> 4, n = i & 15;
            int kk = k >> 5, qd = (k >> 3) & 3, j = k & 7;
            Bl[((kk * 4 + qd) * 16 + n) * 8 + j] = w;
        }
        __syncthreads();
        v8s bfrag[8];
#pragma unroll
        for (int kk = 0; kk < 8; ++kk)
            bfrag[kk] = *(const v8s*)&Bl[(kk * 64 + lane) * 8];
        const unsigned short* x = (const unsigned short*)xp_;
        for (int t0 = blockIdx.x * 8 + wave * 2; t0 < n_tiles; t0 += gridDim.x * 8) {
            int rA = t0 * 16 + col;       rA = rA < n_nodes ? rA : n_nodes - 1;
            int rB = t0 * 16 + 16 + col;  rB = rB < n_nodes ? rB : n_nodes - 1;
            const unsigned short* xpA = x + (size_t)rA * IN_DIM + quad * 8;
            const unsigned short* xpB = x + (size_t)rB * IN_DIM + quad * 8;
            v8s aA[8], aB[8];
#pragma unroll
            for (int kk = 0; kk < 8; ++kk) aA[kk] = *(const v8s*)(xpA + kk * 32);
#pragma unroll
            for (int kk = 0; kk < 8; ++kk) aB[kk] = *(const v8s*)(xpB + kk * 32);
            v4f accA = {0.f, 0.f, 0.f, 0.f};
            v4f accB = {0.f, 0.f, 0.f, 0.f};
#pragma unroll
            for (int kk = 0; kk < 8; ++kk) {
                accA = __builtin_amdgcn_mfma_f32_16x16x32_bf16(aA[kk], bfrag[kk], accA, 0, 0, 0);
                accB = __builtin_amdgcn_mfma_f32_16x16x32_bf16(aB[kk], bfrag[kk], accB, 0, 0, 0);
            }
#pragma unroll
            for (int rg = 0; rg < 4; ++rg) {
                int nA = t0 * 16 + quad * 4 + rg;
                int nB = nA + 16;
                if (nA < n_nodes) m1[(size_t)nA * HID + col] = f2bf(accA[rg]);
                if (nB < n_nodes) m1[(size_t)nB * HID + col] = f2bf(accB[rg]);
            }
        }
    } else {
        // ---------- fp32 x path: split-bf16, fp32-grade ----------
        unsigned short* Bhi = Bbuf;
        unsigned short* Blo = Bbuf + 4096;
        for (int i = t; i < 4096; i += 256) {
            float w = wf32 ? ((const float*)W1p)[i]
                           : bf2f(((const unsigned short*)W1p)[i]);
            unsigned short hi = f2bf(w);
            unsigned short lo = f2bf(w - bf2f(hi));
            int k = i >> 4, n = i & 15;
            int kk = k >> 5, qd = (k >> 3) & 3, j = k & 7;
            int idx = ((kk * 4 + qd) * 16 + n) * 8 + j;
            Bhi[idx] = hi; Blo[idx] = lo;
        }
        __syncthreads();
        const float* x = (const float*)xp_;
        for (int t0 = blockIdx.x * 8 + wave * 2; t0 < n_tiles; t0 += gridDim.x * 8) {
            int rA = t0 * 16 + col;       rA = rA < n_nodes ? rA : n_nodes - 1;
            int rB = t0 * 16 + 16 + col;  rB = rB < n_nodes ? rB : n_nodes - 1;
            const float* xpA = x + (size_t)rA * IN_DIM + quad * 8;
            const float* xpB = x + (size_t)rB * IN_DIM + quad * 8;
            // issue all 32 independent dwordx4 loads before any consume
            float4 uA[16], uB[16];
#pragma unroll
            for (int kk = 0; kk < 8; ++kk) {
                uA[2 * kk]     = *(const float4*)(xpA + kk * 32);
                uA[2 * kk + 1] = *(const float4*)(xpA + kk * 32 + 4);
            }
#pragma unroll
            for (int kk = 0; kk < 8; ++kk) {
                uB[2 * kk]     = *(const float4*)(xpB + kk * 32);
                uB[2 * kk + 1] = *(const float4*)(xpB + kk * 32 + 4);
            }
            v4f accA = {0.f, 0.f, 0.f, 0.f};
            v4f accB = {0.f, 0.f, 0.f, 0.f};
#pragma unroll
            for (int kk = 0; kk < 8; ++kk) {
                float va[8] = {uA[2 * kk].x, uA[2 * kk].y, uA[2 * kk].z, uA[2 * kk].w,
                               uA[2 * kk + 1].x, uA[2 * kk + 1].y, uA[2 * kk + 1].z, uA[2 * kk + 1].w};
                float vb[8] = {uB[2 * kk].x, uB[2 * kk].y, uB[2 * kk].z, uB[2 * kk].w,
                               uB[2 * kk + 1].x, uB[2 * kk + 1].y, uB[2 * kk + 1].z, uB[2 * kk + 1].w};
                v8s ahiA, aloA, ahiB, aloB;
#pragma unroll
                for (int j = 0; j < 8; ++j) {
                    unsigned short hi = f2bf(va[j]);
                    unsigned short lo = f2bf(va[j] - bf2f(hi));
                    ahiA[j] = (short)hi; aloA[j] = (short)lo;
                    hi = f2bf(vb[j]);
                    lo = f2bf(vb[j] - bf2f(hi));
                    ahiB[j] = (short)hi; aloB[j] = (short)lo;
                }
                v8s bh = *(const v8s*)&Bhi[(kk * 64 + lane) * 8];
                v8s bl = *(const v8s*)&Blo[(kk * 64 + lane) * 8];
                accA = __builtin_amdgcn_mfma_f32_16x16x32_bf16(ahiA, bh, accA, 0, 0, 0);
                accA = __builtin_amdgcn_mfma_f32_16x16x32_bf16(ahiA, bl, accA, 0, 0, 0);
                accA = __builtin_amdgcn_mfma_f32_16x16x32_bf16(aloA, bh, accA, 0, 0, 0);
                accB = __builtin_amdgcn_mfma_f32_16x16x32_bf16(ahiB, bh, accB, 0, 0, 0);
                accB = __builtin_amdgcn_mfma_f32_16x16x32_bf16(ahiB, bl, accB, 0, 0, 0);
                accB = __builtin_amdgcn_mfma_f32_16x16x32_bf16(aloB, bh, accB, 0, 0, 0);
            }
#pragma unroll
            for (int rg = 0; rg < 4; ++rg) {
                int nA = t0 * 16 + quad * 4 + rg;
                int nB = nA + 16;
                if (nA < n_nodes) m1[(size_t)nA * HID + col] = f2bf(accA[rg]);
                if (nB < n_nodes) m1[(size_t)nB * HID + col] = f2bf(accB[rg]);
            }
        }
    }
}

// ---------------- gather-sum core: 4 lanes/node, bf16 rows, 16-deep MLP -----
__device__ __forceinline__ v4f gather_bf16(const unsigned short* __restrict__ src,
                                           const int* __restrict__ csr_src,
                                           int beg, int end, int q) {
    float a0 = 0.f, a1 = 0.f, a2 = 0.f, a3 = 0.f;
    int k = beg;
    for (; k + 16 <= end; k += 16) {
        uint2 v[16];
#pragma unroll
        for (int u = 0; u < 16; ++u) {
            int s = csr_src[k + u];
            v[u] = *(const uint2*)(src + (size_t)s * HID + q * 4);
        }
#pragma unroll
        for (int u = 0; u < 16; ++u) {
            a0 += bf2f((unsigned short)(v[u].x));
            a1 += bf2f((unsigned short)(v[u].x >> 16));
            a2 += bf2f((unsigned short)(v[u].y));
            a3 += bf2f((unsigned short)(v[u].y >> 16));
        }
    }
    for (; k + 4 <= end; k += 4) {
        uint2 v[4];
#pragma unroll
        for (int u = 0; u < 4; ++u) {
            int s = csr_src[k + u];
            v[u] = *(const uint2*)(src + (size_t)s * HID + q * 4);
        }
#pragma unroll
        for (int u = 0; u < 4; ++u) {
            a0 += bf2f((unsigned short)(v[u].x));
            a1 += bf2f((unsigned short)(v[u].x >> 16));
            a2 += bf2f((unsigned short)(v[u].y));
            a3 += bf2f((unsigned short)(v[u].y >> 16));
        }
    }
    for (; k < end; ++k) {
        int s = csr_src[k];
        uint2 v = *(const uint2*)(src + (size_t)s * HID + q * 4);
        a0 += bf2f((unsigned short)(v.x));
        a1 += bf2f((unsigned short)(v.x >> 16));
        a2 += bf2f((unsigned short)(v.y));
        a3 += bf2f((unsigned short)(v.y >> 16));
    }
    v4f r = {a0, a1, a2, a3};
    return r;
}

// ---------------- agg1: h = bf16(relu(A . m1 + b1)) -------------------------
__global__ void agg1_kernel(const unsigned short* __restrict__ m1,
                            const int* __restrict__ row_off,
                            const int* __restrict__ csr_src,
                            const void* __restrict__ b1p,
                            unsigned short* __restrict__ h, int n_nodes,
                            const int* __restrict__ flags) {
    int t = blockIdx.x * blockDim.x + threadIdx.x;
    int node = t >> 2;
    if (node >= n_nodes) return;
    int q = t & 3;
    const int wf32 = flags[2];
    v4f a = gather_bf16(m1, csr_src, row_off[node], row_off[node + 1], q);
    float b0, b1v, b2v, b3;
    if (wf32) {
        const float* b = (const float*)b1p + q * 4;
        b0 = b[0]; b1v = b[1]; b2v = b[2]; b3 = b[3];
    } else {
        const unsigned short* b = (const unsigned short*)b1p + q * 4;
        b0 = bf2f(b[0]); b1v = bf2f(b[1]); b2v = bf2f(b[2]); b3 = bf2f(b[3]);
    }
    float r0 = fmaxf(a[0] + b0, 0.f);
    float r1 = fmaxf(a[1] + b1v, 0.f);
    float r2 = fmaxf(a[2] + b2v, 0.f);
    float r3 = fmaxf(a[3] + b3, 0.f);
    uint2 packed;
    packed.x = (unsigned int)f2bf(r0) | ((unsigned int)f2bf(r1) << 16);
    packed.y = (unsigned int)f2bf(r2) | ((unsigned int)f2bf(r3) << 16);
    *(uint2*)(h + (size_t)node * HID + q * 4) = packed;
}

// ---------------- agg2 + out fused: out = (A . h) @ W2 + b2 -----------------
// 4 lanes/node gather h (bf16), partial dots vs W2, 4-lane shfl_xor reduce.
__global__ void agg2_out_kernel(const unsigned short* __restrict__ h,
                                const int* __restrict__ row_off,
                                const int* __restrict__ csr_src,
                                const void* __restrict__ W2p,
                                const void* __restrict__ b2p,
                                void* __restrict__ out, int n_nodes,
                                const int* __restrict__ flags) {
    __shared__ float Ws[HID * OUTD];
    __shared__ float bs[OUTD];
    const int xf32 = flags[1], wf32 = flags[2];
    if (threadIdx.x < HID * OUTD)
        Ws[threadIdx.x] = wf32 ? ((const float*)W2p)[threadIdx.x]
                               : bf2f(((const unsigned short*)W2p)[threadIdx.x]);
    if (threadIdx.x < OUTD)
        bs[threadIdx.x] = wf32 ? ((const float*)b2p)[threadIdx.x]
                               : bf2f(((const unsigned short*)b2p)[threadIdx.x]);
    __syncthreads();

    int t = blockIdx.x * blockDim.x + threadIdx.x;
    int node = t >> 2;
    if (node >= n_nodes) return;
    int q = t & 3;
    v4f a = gather_bf16(h, csr_src, row_off[node], row_off[node + 1], q);

    float o[OUTD];
#pragma unroll
    for (int od = 0; od < OUTD; ++od) {
        float s = 0.f;
#pragma unroll
        for (int j = 0; j < 4; ++j)
            s = fmaf(a[j], Ws[(q * 4 + j) * OUTD + od], s);
        o[od] = s;
    }
#pragma unroll
    for (int od = 0; od < OUTD; ++od) {
        o[od] += __shfl_xor(o[od], 1);
        o[od] += __shfl_xor(o[od], 2);
        o[od] += bs[od];
    }

    if (xf32) {
        float2* po = (float2*)((float*)out + (size_t)node * OUTD);
        if (q == 0) {
            po[0] = make_float2(o[0], o[1]);
            po[1] = make_float2(o[2], o[3]);
        } else if (q == 1) {
            po[2] = make_float2(o[4], o[5]);
            po[3] = make_float2(o[6], o[7]);
        } else if (q == 2) {
            po[4] = make_float2(o[8], o[9]);
        }
    } else {
        unsigned int* po = (unsigned int*)((unsigned short*)out + (size_t)node * OUTD);
        if (q == 0) {
            po[0] = (unsigned int)f2bf(o[0]) | ((unsigned int)f2bf(o[1]) << 16);
            po[1] = (unsigned int)f2bf(o[2]) | ((unsigned int)f2bf(o[3]) << 16);
        } else if (q == 1) {
            po[2] = (unsigned int)f2bf(o[4]) | ((unsigned int)f2bf(o[5]) << 16);
            po[3] = (unsigned int)f2bf(o[6]) | ((unsigned int)f2bf(o[7]) << 16);
        } else if (q == 2) {
            po[4] = (unsigned int)f2bf(o[8]) | ((unsigned int)f2bf(o[9]) << 16);
        }
    }
}

// ---------------- Sentinel: ws_size too small -------------------------------
__global__ void sentinel_kernel(float* __restrict__ out) {
    if (blockIdx.x == 0 && threadIdx.x < 16) out[threadIdx.x] = 123456.0f;
}

extern "C" void kernel_launch(void* const* d_in, const int* in_sizes, int n_in,
                              void* d_out, int out_size, void* d_ws, size_t ws_size,
                              hipStream_t stream) {
    const void* x  = d_in[0];
    const void* ei = d_in[1];
    const void* W1 = d_in[2];
    const void* b1 = d_in[3];
    const void* W2 = d_in[4];
    const void* b2 = d_in[5];

    const int n_nodes = in_sizes[0] / IN_DIM;        // 100000
    const int n_edges = in_sizes[1] / 2;             // 3200000
    const int K = (n_nodes + BKT_W - 1) / BKT_W;     // 391 buckets

    // Workspace layout (256B-aligned):
    // [flags | bucket_cnt | bucket_off | bcur | row_off | csr_src |
    //  pairs-region (aliases bf16 m1,h after csr build; stream-ordered)]
    char* p = (char*)d_ws;
    auto align = [](size_t v) { return (v + 255) & ~(size_t)255; };
    size_t off = 0;
    int* flags      = (int*)(p + off); off = align(off + 256);
    int* bucket_cnt = (int*)(p + off); off = align(off + (size_t)K * 4);
    int* bucket_off = (int*)(p + off); off = align(off + ((size_t)K + 1) * 4);
    int* bcur       = (int*)(p + off); off = align(off + (size_t)K * 4);
    int* row_off    = (int*)(p + off); off = align(off + ((size_t)n_nodes + 1) * 4);
    int* csr_src    = (int*)(p + off); off = align(off + (size_t)n_edges * 4);
    size_t alias_base = off;
    unsigned int* pairs = (unsigned int*)(p + alias_base);
    unsigned short* m1 = (unsigned short*)(p + alias_base);   // bf16 [n_nodes][16]
    unsigned short* h  = m1 + (size_t)n_nodes * HID;          // bf16 [n_nodes][16]
    size_t alias_sz = (size_t)n_edges * 4;                    // packed pairs
    size_t mh_sz = (size_t)n_nodes * HID * 2 * 2;             // m1 + h bf16
    if (mh_sz > alias_sz) alias_sz = mh_sz;
    off = align(alias_base + alias_sz);

    if (ws_size < off) {
        sentinel_kernel<<<1, 64, 0, stream>>>((float*)d_out);
        return;
    }

    const size_t lds_k = (size_t)K * 4;

    // --- CSR build (bucketed, LDS counting-sort, line-efficient writes) ---
    setup_kernel<<<1, 256, 0, stream>>>(x, W1, ei, n_nodes, flags, bucket_cnt, K);
    bhist_kernel<<<1024, 256, lds_k, stream>>>(ei, n_edges, bucket_cnt, flags, K);
    bscan_kernel<<<1, 256, 0, stream>>>(bucket_cnt, K, bucket_off, bcur,
                                        row_off, n_nodes, n_edges);
    part_kernel<<<(n_edges + PART_CH - 1) / PART_CH, 256, 0, stream>>>(
        ei, n_edges, bcur, pairs, flags, K);
    csr_kernel<<<K, 512, 0, stream>>>(pairs, bucket_off, row_off, csr_src, n_nodes);

    // --- layer 1 GEMM (m1 bf16; pairs no longer needed) ---
    {
        int n_tiles16 = (n_nodes + 15) >> 4;          // 6250
        int g1 = (n_tiles16 + 7) / 8;                 // 2 tiles per wave
        gemm1_kernel<<<g1, 256, 0, stream>>>(x, W1, m1, n_nodes, flags);
    }

    // --- layer 1 aggregation ---
    {
        long long threads = (long long)n_nodes * 4;
        agg1_kernel<<<(int)((threads + 255) / 256), 256, 0, stream>>>(
            m1, row_off, csr_src, b1, h, n_nodes, flags);
    }

    // --- layer 2 aggregation + output GEMM fused ---
    {
        long long threads = (long long)n_nodes * 4;
        agg2_out_kernel<<<(int)((threads + 255) / 256), 256, 0, stream>>>(
            h, row_off, csr_src, W2, b2, d_out, n_nodes, flags);
    }
}

// Round 4
// 334.900 us; speedup vs baseline: 2.8053x; 1.0119x over previous
//
#include <hip/hip_runtime.h>
#include <hip/hip_bf16.h>
#include <stdint.h>

#define IN_DIM 256
#define HID 16
#define OUTD 10
#define BKT_SHIFT 8            // 256 nodes per bucket
#define BKT_W 256
#define PART_CH 4096           // edges per partition block
#define EPT 16                 // edges per thread in part (PART_CH/256)

typedef short v8s __attribute__((ext_vector_type(8)));
typedef float v4f __attribute__((ext_vector_type(4)));

__device__ __forceinline__ float bf2f(unsigned short u) {
    return __uint_as_float(((unsigned int)u) << 16);
}
__device__ __forceinline__ unsigned short f2bf(float f) {
    unsigned int u = __float_as_uint(f);
    unsigned int lsb = (u >> 16) & 1u;
    u += 0x7fffu + lsb;  // round-to-nearest-even
    return (unsigned short)(u >> 16);
}

__device__ __forceinline__ int load_dst(const void* ei, int n_edges, int e, int is64) {
    return is64 ? (int)((const long long*)ei)[(size_t)n_edges + e]
                : ((const int*)ei)[(size_t)n_edges + e];
}
__device__ __forceinline__ int load_src(const void* ei, int n_edges, int e, int is64) {
    return is64 ? (int)((const long long*)ei)[e] : ((const int*)ei)[e];
}

// ---------------- setup: parallel dtype detect + zero bucket counters -------
__global__ void setup_kernel(const void* __restrict__ x,
                             const void* __restrict__ W1,
                             const void* __restrict__ ei,
                             int n_nodes, int* __restrict__ flags,
                             int* __restrict__ bucket_cnt, int K) {
    int t = threadIdx.x;
    for (int i = t; i < K; i += blockDim.x) bucket_cnt[i] = 0;
    if (t < 64) {
        const unsigned short* xs = (const unsigned short*)x;
        const unsigned short* ws = (const unsigned short*)W1;
        bool badx = false, badw = false;
#pragma unroll
        for (int q = 0; q < 4; ++q) {
            float vx = bf2f(xs[t + 64 * q]);
            float vw = bf2f(ws[t + 64 * q]);
            if (!(vx > -1e4f && vx < 1e4f)) badx = true;
            if (!(vw > -1e4f && vw < 1e4f)) badw = true;
        }
        const unsigned long long* e64 = (const unsigned long long*)ei;
        bool big = false;
#pragma unroll
        for (int q = 0; q < 2; ++q)
            if (e64[t + 64 * q] >= (unsigned long long)n_nodes) big = true;
        int xf32 = __any(badx) ? 1 : 0;
        int wf32 = __any(badw) ? 1 : 0;
        int is64 = __any(big) ? 0 : 1;
        if (t == 0) { flags[0] = is64; flags[1] = xf32; flags[2] = wf32; }
    }
}

// ---------------- w1prep: bf16 hi/lo split of W1 in MFMA-fragment layout ----
// W1split[idx] hi, W1split[4096+idx] lo; idx = (kk*64 + lane)*8 + j so a
// lane's per-kk fragment is one coalesced 16B load. Removes per-block LDS
// staging + syncthreads + bank conflicts from gemm1.
__global__ void w1prep_kernel(const void* __restrict__ W1p,
                              unsigned short* __restrict__ W1split,
                              const int* __restrict__ flags) {
    const int wf32 = flags[2];
    int i = threadIdx.x + blockIdx.x * blockDim.x;   // 0..4095 (i = k*16 + n)
    if (i >= IN_DIM * HID) return;
    float w = wf32 ? ((const float*)W1p)[i]
                   : bf2f(((const unsigned short*)W1p)[i]);
    unsigned short hi = f2bf(w);
    unsigned short lo = f2bf(w - bf2f(hi));
    int k = i >> 4, n = i & 15;
    int kk = k >> 5, qd = (k >> 3) & 3, j = k & 7;
    int idx = ((kk * 4 + qd) * 16 + n) * 8 + j;      // = (kk*64 + lane)*8 + j
    W1split[idx] = hi;
    W1split[4096 + idx] = lo;
}

// ---------------- bucket histogram ------------------------------------------
__global__ void bhist_kernel(const void* __restrict__ ei, int n_edges,
                             int* __restrict__ bucket_cnt,
                             const int* __restrict__ flags, int K) {
    extern __shared__ int lh[];
    for (int i = threadIdx.x; i < K; i += blockDim.x) lh[i] = 0;
    __syncthreads();
    int is64 = flags[0];
    int t = blockIdx.x * blockDim.x + threadIdx.x;
    int stride = gridDim.x * blockDim.x;
    for (int e = t; e < n_edges; e += stride) {
        int d = load_dst(ei, n_edges, e, is64);
        atomicAdd(&lh[d >> BKT_SHIFT], 1);
    }
    __syncthreads();
    for (int i = threadIdx.x; i < K; i += blockDim.x)
        if (lh[i]) atomicAdd(&bucket_cnt[i], lh[i]);
}

// ---------------- bucket scan (1 block) -------------------------------------
__global__ void bscan_kernel(const int* __restrict__ bucket_cnt, int K,
                             int* __restrict__ bucket_off, int* __restrict__ bcur,
                             int* __restrict__ row_off, int n_nodes, int n_edges) {
    __shared__ int ts[256];
    int t = threadIdx.x;
    const int KP = (K + 255) / 256;   // <= 8
    int base = t * KP;
    int local[8];
    int s = 0;
    for (int q = 0; q < KP; ++q) {
        int idx = base + q;
        int v = (idx < K) ? bucket_cnt[idx] : 0;
        local[q] = v; s += v;
    }
    ts[t] = s;
    __syncthreads();
    for (int off = 1; off < 256; off <<= 1) {
        int v = (t >= off) ? ts[t - off] : 0;
        __syncthreads();
        ts[t] += v;
        __syncthreads();
    }
    int ex = ts[t] - s;
    for (int q = 0; q < KP; ++q) {
        int idx = base + q;
        if (idx < K) { bucket_off[idx] = ex; bcur[idx] = ex; }
        ex += local[q];
    }
    if (t == 255) bucket_off[K] = ex;
    if (t == 0) row_off[n_nodes] = n_edges;
}

// ---------------- partition: in-LDS counting sort + coalesced flush ---------
// pair = (src << 8) | (dst & 255): 4B packed; output sorted by bucket.
__global__ void part_kernel(const void* __restrict__ ei, int n_edges,
                            int* __restrict__ bcur, unsigned int* __restrict__ pairs,
                            const int* __restrict__ flags, int K) {
    __shared__ int lh[512];                  // counts, then placement cursor
    __shared__ int gdelta[512];              // gstart[b] - lstart[b]
    __shared__ int ts[256];
    __shared__ unsigned int spairs[PART_CH]; // 16 KiB
    __shared__ unsigned short sbkt[PART_CH]; // 8 KiB
    int begin = blockIdx.x * PART_CH;
    int is64 = flags[0];
    int t = threadIdx.x;
    lh[t] = 0; lh[t + 256] = 0;

    int dloc[EPT];
#pragma unroll
    for (int i = 0; i < EPT; ++i) {
        int e = begin + i * 256 + t;
        dloc[i] = (e < n_edges) ? load_dst(ei, n_edges, e, is64) : -1;
    }
    __syncthreads();
#pragma unroll
    for (int i = 0; i < EPT; ++i)
        if (dloc[i] >= 0) atomicAdd(&lh[dloc[i] >> BKT_SHIFT], 1);
    __syncthreads();

    // block scan over 512 bucket counts (thread t owns entries 2t, 2t+1)
    int c0 = lh[2 * t], c1 = lh[2 * t + 1];
    int s = c0 + c1;
    ts[t] = s;
    __syncthreads();
    for (int off = 1; off < 256; off <<= 1) {
        int v = (t >= off) ? ts[t - off] : 0;
        __syncthreads();
        ts[t] += v;
        __syncthreads();
    }
    int ex = ts[t] - s;
    // reserve global runs; cursor = local exclusive start
    if (c0 > 0) gdelta[2 * t]     = atomicAdd(&bcur[2 * t], c0) - ex;
    if (c1 > 0) gdelta[2 * t + 1] = atomicAdd(&bcur[2 * t + 1], c1) - (ex + c0);
    __syncthreads();   // everyone done reading lh counts before overwrite
    lh[2 * t] = ex; lh[2 * t + 1] = ex + c0;
    __syncthreads();

    // place into LDS, sorted by bucket
#pragma unroll
    for (int i = 0; i < EPT; ++i) {
        int e = begin + i * 256 + t;
        if (dloc[i] >= 0) {
            int srcv = load_src(ei, n_edges, e, is64);
            int b = dloc[i] >> BKT_SHIFT;
            int lpos = atomicAdd(&lh[b], 1);
            spairs[lpos] = ((unsigned)srcv << 8) | ((unsigned)dloc[i] & (BKT_W - 1));
            sbkt[lpos] = (unsigned short)b;
        }
    }
    __syncthreads();

    // coalesced flush: ascending j walks bucket runs contiguously
    int total = n_edges - begin; if (total > PART_CH) total = PART_CH;
    for (int j = t; j < total; j += 256)
        pairs[gdelta[sbkt[j]] + j] = spairs[j];
}

// ---------------- per-bucket CSR build (256-node buckets, 512 thr) ----------
__global__ void csr_kernel(const unsigned int* __restrict__ pairs,
                           const int* __restrict__ bucket_off,
                           int* __restrict__ row_off, int* __restrict__ csr_src,
                           int n_nodes) {
    __shared__ int deg[BKT_W];
    __shared__ int cur[BKT_W];
    __shared__ int ts[BKT_W];
    int blk = blockIdx.x;
    int nbase = blk << BKT_SHIFT;
    int NL = n_nodes - nbase; if (NL > BKT_W) NL = BKT_W;
    int beg = bucket_off[blk], end = bucket_off[blk + 1];
    int t = threadIdx.x;
    if (t < BKT_W) deg[t] = 0;
    __syncthreads();
    for (int k = beg + t; k < end; k += blockDim.x)
        atomicAdd(&deg[pairs[k] & (BKT_W - 1)], 1);
    __syncthreads();
    if (t < BKT_W) ts[t] = deg[t];
    __syncthreads();
    for (int off = 1; off < BKT_W; off <<= 1) {
        int v = 0;
        if (t < BKT_W && t >= off) v = ts[t - off];
        __syncthreads();
        if (t < BKT_W) ts[t] += v;
        __syncthreads();
    }
    if (t < BKT_W) {
        int ex = beg + ts[t] - deg[t];
        cur[t] = ex;
        if (t < NL) row_off[nbase + t] = ex;
    }
    __syncthreads();
    for (int k = beg + t; k < end; k += blockDim.x) {
        unsigned int p = pairs[k];
        int pos = atomicAdd(&cur[p & (BKT_W - 1)], 1);
        csr_src[pos] = (int)(p >> 8);
    }
}

// ---------------- gemm1: m1 = bf16(x @ W1), LDS-free streaming --------------
// 1 tile (16 nodes) per wave, one-shot. B-fragments come from the w1prep
// split table (L1/L2-resident, coalesced 16B loads) -> no LDS, no barriers.
// launch_bounds(256,4) gives a 128-VGPR budget so all 16 x-loads stay in
// flight (prior build: VGPR=64 -> loads were re-batched serially, 60us).
__global__ __launch_bounds__(256, 4) void gemm1_kernel(
        const void* __restrict__ xp_,
        const unsigned short* __restrict__ W1split,
        unsigned short* __restrict__ m1, int n_nodes,
        const int* __restrict__ flags) {
    const int xf32 = flags[1];
    int t = threadIdx.x;
    int lane = t & 63;
    int wave = t >> 6;
    int col  = lane & 15;
    int quad = lane >> 4;
    int n_tiles = (n_nodes + 15) >> 4;
    const unsigned short* Whi = W1split;
    const unsigned short* Wlo = W1split + 4096;

    if (!xf32) {
        // ---------- bf16 x path ----------
        const unsigned short* x = (const unsigned short*)xp_;
        for (int tile = blockIdx.x * 4 + wave; tile < n_tiles; tile += gridDim.x * 4) {
            int row = tile * 16 + col;
            int r = row < n_nodes ? row : n_nodes - 1;
            const unsigned short* xp = x + (size_t)r * IN_DIM + quad * 8;
            v8s a[8];
#pragma unroll
            for (int kk = 0; kk < 8; ++kk)
                a[kk] = *(const v8s*)(xp + kk * 32);
            v4f acc1 = {0.f, 0.f, 0.f, 0.f};
            v4f acc2 = {0.f, 0.f, 0.f, 0.f};
#pragma unroll
            for (int kk = 0; kk < 8; ++kk) {
                v8s bh = *(const v8s*)&Whi[(kk * 64 + lane) * 8];
                v8s bl = *(const v8s*)&Wlo[(kk * 64 + lane) * 8];
                acc1 = __builtin_amdgcn_mfma_f32_16x16x32_bf16(a[kk], bh, acc1, 0, 0, 0);
                acc2 = __builtin_amdgcn_mfma_f32_16x16x32_bf16(a[kk], bl, acc2, 0, 0, 0);
            }
#pragma unroll
            for (int rg = 0; rg < 4; ++rg) {
                int node = tile * 16 + quad * 4 + rg;
                if (node < n_nodes)
                    m1[(size_t)node * HID + col] = f2bf(acc1[rg] + acc2[rg]);
            }
        }
    } else {
        // ---------- fp32 x path: split-bf16, fp32-grade ----------
        const float* x = (const float*)xp_;
        for (int tile = blockIdx.x * 4 + wave; tile < n_tiles; tile += gridDim.x * 4) {
            int row = tile * 16 + col;
            int r = row < n_nodes ? row : n_nodes - 1;
            const float* xp = x + (size_t)r * IN_DIM + quad * 8;
            // 16 independent dwordx4 loads, all in flight before any consume
            float4 u[16];
#pragma unroll
            for (int kk = 0; kk < 8; ++kk) {
                u[2 * kk]     = *(const float4*)(xp + kk * 32);
                u[2 * kk + 1] = *(const float4*)(xp + kk * 32 + 4);
            }
            v4f acc1 = {0.f, 0.f, 0.f, 0.f};   // ahi*bh chain
            v4f acc2 = {0.f, 0.f, 0.f, 0.f};   // ahi*bl + alo*bh chain
#pragma unroll
            for (int kk = 0; kk < 8; ++kk) {
                float uv[8] = {u[2 * kk].x,     u[2 * kk].y,
                               u[2 * kk].z,     u[2 * kk].w,
                               u[2 * kk + 1].x, u[2 * kk + 1].y,
                               u[2 * kk + 1].z, u[2 * kk + 1].w};
                v8s ahi, alo;
#pragma unroll
                for (int j = 0; j < 8; ++j) {
                    unsigned short hi = f2bf(uv[j]);
                    unsigned short lo = f2bf(uv[j] - bf2f(hi));
                    ahi[j] = (short)hi; alo[j] = (short)lo;
                }
                v8s bh = *(const v8s*)&Whi[(kk * 64 + lane) * 8];
                v8s bl = *(const v8s*)&Wlo[(kk * 64 + lane) * 8];
                acc1 = __builtin_amdgcn_mfma_f32_16x16x32_bf16(ahi, bh, acc1, 0, 0, 0);
                acc2 = __builtin_amdgcn_mfma_f32_16x16x32_bf16(ahi, bl, acc2, 0, 0, 0);
                acc2 = __builtin_amdgcn_mfma_f32_16x16x32_bf16(alo, bh, acc2, 0, 0, 0);
            }
#pragma unroll
            for (int rg = 0; rg < 4; ++rg) {
                int node = tile * 16 + quad * 4 + rg;
                if (node < n_nodes)
                    m1[(size_t)node * HID + col] = f2bf(acc1[rg] + acc2[rg]);
            }
        }
    }
}

// ---------------- gather-sum core: 4 lanes/node, bf16 rows, 16-deep MLP -----
__device__ __forceinline__ v4f gather_bf16(const unsigned short* __restrict__ src,
                                           const int* __restrict__ csr_src,
                                           int beg, int end, int q) {
    float a0 = 0.f, a1 = 0.f, a2 = 0.f, a3 = 0.f;
    int k = beg;
    for (; k + 16 <= end; k += 16) {
        uint2 v[16];
#pragma unroll
        for (int u = 0; u < 16; ++u) {
            int s = csr_src[k + u];
            v[u] = *(const uint2*)(src + (size_t)s * HID + q * 4);
        }
#pragma unroll
        for (int u = 0; u < 16; ++u) {
            a0 += bf2f((unsigned short)(v[u].x));
            a1 += bf2f((unsigned short)(v[u].x >> 16));
            a2 += bf2f((unsigned short)(v[u].y));
            a3 += bf2f((unsigned short)(v[u].y >> 16));
        }
    }
    for (; k + 4 <= end; k += 4) {
        uint2 v[4];
#pragma unroll
        for (int u = 0; u < 4; ++u) {
            int s = csr_src[k + u];
            v[u] = *(const uint2*)(src + (size_t)s * HID + q * 4);
        }
#pragma unroll
        for (int u = 0; u < 4; ++u) {
            a0 += bf2f((unsigned short)(v[u].x));
            a1 += bf2f((unsigned short)(v[u].x >> 16));
            a2 += bf2f((unsigned short)(v[u].y));
            a3 += bf2f((unsigned short)(v[u].y >> 16));
        }
    }
    for (; k < end; ++k) {
        int s = csr_src[k];
        uint2 v = *(const uint2*)(src + (size_t)s * HID + q * 4);
        a0 += bf2f((unsigned short)(v.x));
        a1 += bf2f((unsigned short)(v.x >> 16));
        a2 += bf2f((unsigned short)(v.y));
        a3 += bf2f((unsigned short)(v.y >> 16));
    }
    v4f r = {a0, a1, a2, a3};
    return r;
}

// ---------------- agg1: h = bf16(relu(A . m1 + b1)) -------------------------
__global__ void agg1_kernel(const unsigned short* __restrict__ m1,
                            const int* __restrict__ row_off,
                            const int* __restrict__ csr_src,
                            const void* __restrict__ b1p,
                            unsigned short* __restrict__ h, int n_nodes,
                            const int* __restrict__ flags) {
    int t = blockIdx.x * blockDim.x + threadIdx.x;
    int node = t >> 2;
    if (node >= n_nodes) return;
    int q = t & 3;
    const int wf32 = flags[2];
    v4f a = gather_bf16(m1, csr_src, row_off[node], row_off[node + 1], q);
    float b0, b1v, b2v, b3;
    if (wf32) {
        const float* b = (const float*)b1p + q * 4;
        b0 = b[0]; b1v = b[1]; b2v = b[2]; b3 = b[3];
    } else {
        const unsigned short* b = (const unsigned short*)b1p + q * 4;
        b0 = bf2f(b[0]); b1v = bf2f(b[1]); b2v = bf2f(b[2]); b3 = bf2f(b[3]);
    }
    float r0 = fmaxf(a[0] + b0, 0.f);
    float r1 = fmaxf(a[1] + b1v, 0.f);
    float r2 = fmaxf(a[2] + b2v, 0.f);
    float r3 = fmaxf(a[3] + b3, 0.f);
    uint2 packed;
    packed.x = (unsigned int)f2bf(r0) | ((unsigned int)f2bf(r1) << 16);
    packed.y = (unsigned int)f2bf(r2) | ((unsigned int)f2bf(r3) << 16);
    *(uint2*)(h + (size_t)node * HID + q * 4) = packed;
}

// ---------------- agg2 + out fused: out = (A . h) @ W2 + b2 -----------------
// 4 lanes/node gather h (bf16), partial dots vs W2, 4-lane shfl_xor reduce.
__global__ void agg2_out_kernel(const unsigned short* __restrict__ h,
                                const int* __restrict__ row_off,
                                const int* __restrict__ csr_src,
                                const void* __restrict__ W2p,
                                const void* __restrict__ b2p,
                                void* __restrict__ out, int n_nodes,
                                const int* __restrict__ flags) {
    __shared__ float Ws[HID * OUTD];
    __shared__ float bs[OUTD];
    const int xf32 = flags[1], wf32 = flags[2];
    if (threadIdx.x < HID * OUTD)
        Ws[threadIdx.x] = wf32 ? ((const float*)W2p)[threadIdx.x]
                               : bf2f(((const unsigned short*)W2p)[threadIdx.x]);
    if (threadIdx.x < OUTD)
        bs[threadIdx.x] = wf32 ? ((const float*)b2p)[threadIdx.x]
                               : bf2f(((const unsigned short*)b2p)[threadIdx.x]);
    __syncthreads();

    int t = blockIdx.x * blockDim.x + threadIdx.x;
    int node = t >> 2;
    if (node >= n_nodes) return;
    int q = t & 3;
    v4f a = gather_bf16(h, csr_src, row_off[node], row_off[node + 1], q);

    float o[OUTD];
#pragma unroll
    for (int od = 0; od < OUTD; ++od) {
        float s = 0.f;
#pragma unroll
        for (int j = 0; j < 4; ++j)
            s = fmaf(a[j], Ws[(q * 4 + j) * OUTD + od], s);
        o[od] = s;
    }
#pragma unroll
    for (int od = 0; od < OUTD; ++od) {
        o[od] += __shfl_xor(o[od], 1);
        o[od] += __shfl_xor(o[od], 2);
        o[od] += bs[od];
    }

    if (xf32) {
        float2* po = (float2*)((float*)out + (size_t)node * OUTD);
        if (q == 0) {
            po[0] = make_float2(o[0], o[1]);
            po[1] = make_float2(o[2], o[3]);
        } else if (q == 1) {
            po[2] = make_float2(o[4], o[5]);
            po[3] = make_float2(o[6], o[7]);
        } else if (q == 2) {
            po[4] = make_float2(o[8], o[9]);
        }
    } else {
        unsigned int* po = (unsigned int*)((unsigned short*)out + (size_t)node * OUTD);
        if (q == 0) {
            po[0] = (unsigned int)f2bf(o[0]) | ((unsigned int)f2bf(o[1]) << 16);
            po[1] = (unsigned int)f2bf(o[2]) | ((unsigned int)f2bf(o[3]) << 16);
        } else if (q == 1) {
            po[2] = (unsigned int)f2bf(o[4]) | ((unsigned int)f2bf(o[5]) << 16);
            po[3] = (unsigned int)f2bf(o[6]) | ((unsigned int)f2bf(o[7]) << 16);
        } else if (q == 2) {
            po[4] = (unsigned int)f2bf(o[8]) | ((unsigned int)f2bf(o[9]) << 16);
        }
    }
}

// ---------------- Sentinel: ws_size too small -------------------------------
__global__ void sentinel_kernel(float* __restrict__ out) {
    if (blockIdx.x == 0 && threadIdx.x < 16) out[threadIdx.x] = 123456.0f;
}

extern "C" void kernel_launch(void* const* d_in, const int* in_sizes, int n_in,
                              void* d_out, int out_size, void* d_ws, size_t ws_size,
                              hipStream_t stream) {
    const void* x  = d_in[0];
    const void* ei = d_in[1];
    const void* W1 = d_in[2];
    const void* b1 = d_in[3];
    const void* W2 = d_in[4];
    const void* b2 = d_in[5];

    const int n_nodes = in_sizes[0] / IN_DIM;        // 100000
    const int n_edges = in_sizes[1] / 2;             // 3200000
    const int K = (n_nodes + BKT_W - 1) / BKT_W;     // 391 buckets

    // Workspace layout (256B-aligned):
    // [flags | w1split | bucket_cnt | bucket_off | bcur | row_off | csr_src |
    //  pairs-region (aliases bf16 m1,h after csr build; stream-ordered)]
    char* p = (char*)d_ws;
    auto align = [](size_t v) { return (v + 255) & ~(size_t)255; };
    size_t off = 0;
    int* flags      = (int*)(p + off); off = align(off + 256);
    unsigned short* w1split = (unsigned short*)(p + off); off = align(off + 8192 * 2);
    int* bucket_cnt = (int*)(p + off); off = align(off + (size_t)K * 4);
    int* bucket_off = (int*)(p + off); off = align(off + ((size_t)K + 1) * 4);
    int* bcur       = (int*)(p + off); off = align(off + (size_t)K * 4);
    int* row_off    = (int*)(p + off); off = align(off + ((size_t)n_nodes + 1) * 4);
    int* csr_src    = (int*)(p + off); off = align(off + (size_t)n_edges * 4);
    size_t alias_base = off;
    unsigned int* pairs = (unsigned int*)(p + alias_base);
    unsigned short* m1 = (unsigned short*)(p + alias_base);   // bf16 [n_nodes][16]
    unsigned short* h  = m1 + (size_t)n_nodes * HID;          // bf16 [n_nodes][16]
    size_t alias_sz = (size_t)n_edges * 4;                    // packed pairs
    size_t mh_sz = (size_t)n_nodes * HID * 2 * 2;             // m1 + h bf16
    if (mh_sz > alias_sz) alias_sz = mh_sz;
    off = align(alias_base + alias_sz);

    if (ws_size < off) {
        sentinel_kernel<<<1, 64, 0, stream>>>((float*)d_out);
        return;
    }

    const size_t lds_k = (size_t)K * 4;

    // --- CSR build (bucketed, LDS counting-sort, line-efficient writes) ---
    setup_kernel<<<1, 256, 0, stream>>>(x, W1, ei, n_nodes, flags, bucket_cnt, K);
    w1prep_kernel<<<16, 256, 0, stream>>>(W1, w1split, flags);
    bhist_kernel<<<1024, 256, lds_k, stream>>>(ei, n_edges, bucket_cnt, flags, K);
    bscan_kernel<<<1, 256, 0, stream>>>(bucket_cnt, K, bucket_off, bcur,
                                        row_off, n_nodes, n_edges);
    part_kernel<<<(n_edges + PART_CH - 1) / PART_CH, 256, 0, stream>>>(
        ei, n_edges, bcur, pairs, flags, K);
    csr_kernel<<<K, 512, 0, stream>>>(pairs, bucket_off, row_off, csr_src, n_nodes);

    // --- layer 1 GEMM (m1 bf16; pairs no longer needed) ---
    {
        int n_tiles16 = (n_nodes + 15) >> 4;          // 6250
        int g1 = (n_tiles16 + 3) / 4;                 // 1 tile per wave, 1563 blocks
        gemm1_kernel<<<g1, 256, 0, stream>>>(x, w1split, m1, n_nodes, flags);
    }

    // --- layer 1 aggregation ---
    {
        long long threads = (long long)n_nodes * 4;
        agg1_kernel<<<(int)((threads + 255) / 256), 256, 0, stream>>>(
            m1, row_off, csr_src, b1, h, n_nodes, flags);
    }

    // --- layer 2 aggregation + output GEMM fused ---
    {
        long long threads = (long long)n_nodes * 4;
        agg2_out_kernel<<<(int)((threads + 255) / 256), 256, 0, stream>>>(
            h, row_off, csr_src, W2, b2, d_out, n_nodes, flags);
    }
}